// Round 1
// baseline (272.933 us; speedup 1.0000x reference)
//
#include <hip/hip_runtime.h>
#include <math.h>

namespace {
constexpr int BATCH = 4;
constexpr int DDIM  = 128;
constexpr int HDIM  = 192;
constexpr int WDIM  = 192;
constexpr long long NTOT = (long long)BATCH * DDIM * HDIM * WDIM; // 18,874,368
constexpr int N4  = (int)(NTOT / 4);   // 4,718,592 float4 groups
constexpr int GW  = WDIM / 4;          // 48 groups per W-row
constexpr int HS4 = GW;                // group stride for h +/- 1
constexpr int DS4 = GW * HDIM;         // group stride for d +/- 1 (9216)
constexpr int NDSC = 4 * 1 * 8 * 12 * 12; // 4608
constexpr int BLOCK = 256;
constexpr int GRID  = 4608;            // 4 groups per thread exactly
}

__device__ __forceinline__ float4 ld4(const float* __restrict__ p, int g) {
    return *(const float4*)(p + 4LL * g);
}

__global__ __launch_bounds__(BLOCK) void vol_kernel(const float* __restrict__ p,
                                                    const float* __restrict__ y,
                                                    float* __restrict__ acc) {
    float l1 = 0.f, gd = 0.f;
    const int stride = GRID * BLOCK;
    for (int g = blockIdx.x * BLOCK + threadIdx.x; g < N4; g += stride) {
        const int gw   = g % GW;
        const int rest = g / GW;
        const int h    = rest % HDIM;
        const int d    = (rest / HDIM) % DDIM;

        const float4 yc = ld4(y, g);
        const float4 pc = ld4(p, g);

        // ---- L1 ----
        l1 += fabsf(yc.x - pc.x) + fabsf(yc.y - pc.y)
            + fabsf(yc.z - pc.z) + fabsf(yc.w - pc.w);

        // ---- W axis gradient (within group + 2 boundary scalars) ----
        {
            const long long base = 4LL * g;
            float yl = 0.f, pl = 0.f, yr = 0.f, pr = 0.f;
            if (gw > 0)      { yl = y[base - 1]; pl = p[base - 1]; }
            if (gw < GW - 1) { yr = y[base + 4]; pr = p[base + 4]; }
            float gy, gp, t;
            gy = (gw == 0) ? (yc.y - yc.x) : (yc.y - yl) * 0.5f;
            gp = (gw == 0) ? (pc.y - pc.x) : (pc.y - pl) * 0.5f;
            t = fabsf(gy) - fabsf(gp); gd += t * t;
            gy = (yc.z - yc.x) * 0.5f; gp = (pc.z - pc.x) * 0.5f;
            t = fabsf(gy) - fabsf(gp); gd += t * t;
            gy = (yc.w - yc.y) * 0.5f; gp = (pc.w - pc.y) * 0.5f;
            t = fabsf(gy) - fabsf(gp); gd += t * t;
            gy = (gw == GW - 1) ? (yc.w - yc.z) : (yr - yc.z) * 0.5f;
            gp = (gw == GW - 1) ? (pc.w - pc.z) : (pr - pc.z) * 0.5f;
            t = fabsf(gy) - fabsf(gp); gd += t * t;
        }

        // ---- H axis gradient ----
        {
            float4 ym, yp_, pm, pp_;
            float s;
            if (h == 0) {
                ym = yc; pm = pc;
                yp_ = ld4(y, g + HS4); pp_ = ld4(p, g + HS4); s = 1.f;
            } else if (h == HDIM - 1) {
                ym = ld4(y, g - HS4); pm = ld4(p, g - HS4);
                yp_ = yc; pp_ = pc; s = 1.f;
            } else {
                ym = ld4(y, g - HS4); pm = ld4(p, g - HS4);
                yp_ = ld4(y, g + HS4); pp_ = ld4(p, g + HS4); s = 0.5f;
            }
            float t;
            t = fabsf((yp_.x - ym.x) * s) - fabsf((pp_.x - pm.x) * s); gd += t * t;
            t = fabsf((yp_.y - ym.y) * s) - fabsf((pp_.y - pm.y) * s); gd += t * t;
            t = fabsf((yp_.z - ym.z) * s) - fabsf((pp_.z - pm.z) * s); gd += t * t;
            t = fabsf((yp_.w - ym.w) * s) - fabsf((pp_.w - pm.w) * s); gd += t * t;
        }

        // ---- D axis gradient ----
        {
            float4 ym, yp_, pm, pp_;
            float s;
            if (d == 0) {
                ym = yc; pm = pc;
                yp_ = ld4(y, g + DS4); pp_ = ld4(p, g + DS4); s = 1.f;
            } else if (d == DDIM - 1) {
                ym = ld4(y, g - DS4); pm = ld4(p, g - DS4);
                yp_ = yc; pp_ = pc; s = 1.f;
            } else {
                ym = ld4(y, g - DS4); pm = ld4(p, g - DS4);
                yp_ = ld4(y, g + DS4); pp_ = ld4(p, g + DS4); s = 0.5f;
            }
            float t;
            t = fabsf((yp_.x - ym.x) * s) - fabsf((pp_.x - pm.x) * s); gd += t * t;
            t = fabsf((yp_.y - ym.y) * s) - fabsf((pp_.y - pm.y) * s); gd += t * t;
            t = fabsf((yp_.z - ym.z) * s) - fabsf((pp_.z - pm.z) * s); gd += t * t;
            t = fabsf((yp_.w - ym.w) * s) - fabsf((pp_.w - pm.w) * s); gd += t * t;
        }
    }

    // ---- block reduction: wave shuffle (64 lanes) then LDS across 4 waves ----
    __shared__ float lds1[4], lds2[4];
    #pragma unroll
    for (int off = 32; off > 0; off >>= 1) {
        l1 += __shfl_down(l1, off, 64);
        gd += __shfl_down(gd, off, 64);
    }
    const int lane = threadIdx.x & 63;
    const int wave = threadIdx.x >> 6;
    if (lane == 0) { lds1[wave] = l1; lds2[wave] = gd; }
    __syncthreads();
    if (threadIdx.x == 0) {
        atomicAdd(&acc[0], lds1[0] + lds1[1] + lds1[2] + lds1[3]);
        atomicAdd(&acc[1], lds2[0] + lds2[1] + lds2[2] + lds2[3]);
    }
}

// BCE over the small discriminator tensor + final combine. Single block.
__global__ __launch_bounds__(BLOCK) void finalize_kernel(const float* __restrict__ dsc,
                                                         const float* __restrict__ acc,
                                                         float* __restrict__ out) {
    float s = 0.f;
    for (int i = threadIdx.x; i < NDSC; i += BLOCK) {
        const float x = dsc[i];
        // target is zeros: max(x,0) - x*0 + log1p(exp(-|x|))
        s += fmaxf(x, 0.f) + log1pf(expf(-fabsf(x)));
    }
    __shared__ float lds[4];
    #pragma unroll
    for (int off = 32; off > 0; off >>= 1)
        s += __shfl_down(s, off, 64);
    if ((threadIdx.x & 63) == 0) lds[threadIdx.x >> 6] = s;
    __syncthreads();
    if (threadIdx.x == 0) {
        const float bce = (lds[0] + lds[1] + lds[2] + lds[3]) / (float)NDSC;
        const float l1m = acc[0] / (float)NTOT;
        const float gdm = acc[1] / (float)NTOT;  // sums all 3 axes' terms; each mean over NTOT
        out[0] = bce + 100.f * (l1m + gdm);
    }
}

extern "C" void kernel_launch(void* const* d_in, const int* in_sizes, int n_in,
                              void* d_out, int out_size, void* d_ws, size_t ws_size,
                              hipStream_t stream) {
    const float* dsc_fake = (const float*)d_in[0];
    const float* predicts = (const float*)d_in[1];
    const float* y_data   = (const float*)d_in[2];
    // d_in[3] (zeros) unused: target==0 makes the -x*target term vanish.
    float* acc = (float*)d_ws;
    float* out = (float*)d_out;

    hipMemsetAsync(d_ws, 0, 2 * sizeof(float), stream);
    vol_kernel<<<GRID, BLOCK, 0, stream>>>(predicts, y_data, acc);
    finalize_kernel<<<1, BLOCK, 0, stream>>>(dsc_fake, acc, out);
}

// Round 2
// 217.272 us; speedup vs baseline: 1.2562x; 1.2562x over previous
//
#include <hip/hip_runtime.h>
#include <math.h>

namespace {
constexpr int BATCH = 4;
constexpr int DDIM  = 128;
constexpr int HDIM  = 192;
constexpr int WDIM  = 192;
constexpr long long NTOT = (long long)BATCH * DDIM * HDIM * WDIM; // 18,874,368
constexpr int GW   = WDIM / 4;          // 48 float4 groups per W-row
constexpr int HS4  = GW;                // group stride for h +/- 1
constexpr int DS4  = GW * HDIM;         // group stride for d +/- 1 (9216)
constexpr int NDSC = 4 * 1 * 8 * 12 * 12; // 4608
constexpr int BLOCK = 256;
constexpr int DC    = 16;               // depth steps per thread (chunk)
constexpr int NCH   = DDIM / DC;        // 8 chunks
constexpr int NCOL  = BATCH * HDIM * GW;  // 36,864 columns
constexpr int NTHREADS = NCOL * NCH;      // 294,912
constexpr int GRID  = NTHREADS / BLOCK;   // 1152 blocks
}

__device__ __forceinline__ float4 ld4(const float* __restrict__ p, long long g) {
    return *(const float4*)(p + 4LL * g);
}

// Each thread owns one (b, h, gw) float4 column and marches 16 steps along D,
// keeping the d-1 / d / d+1 planes of its own group in registers (no D-neighbor
// loads). Edge handling is branchless: neighbor offsets are clamped to the
// center, and the scale s is 1 at edges (one-sided diff) / 0.5 interior.
__global__ __launch_bounds__(BLOCK, 4) void vol_kernel(const float* __restrict__ p,
                                                       const float* __restrict__ y,
                                                       float* __restrict__ acc) {
    const int t   = blockIdx.x * BLOCK + threadIdx.x;
    const int gw  = t % GW;
    int rest      = t / GW;
    const int h   = rest % HDIM; rest /= HDIM;
    const int b   = rest % BATCH;
    const int chunk = rest / BATCH;
    const int d0  = chunk * DC;

    // per-thread branchless edge constants
    const int   hmo = (h > 0)        ? HS4 : 0;
    const int   hpo = (h < HDIM - 1) ? HS4 : 0;
    const float sh  = (h == 0 || h == HDIM - 1) ? 1.f : 0.5f;
    const int   wlo = (gw > 0)       ? -1 : 0;
    const int   wro = (gw < GW - 1)  ? 4 : 3;
    const float swx = (gw == 0)      ? 1.f : 0.5f;
    const float sww = (gw == GW - 1) ? 1.f : 0.5f;

    long long g = (((long long)b * DDIM + d0) * HDIM + h) * GW + gw;

    // init register pipeline: ym at d0-1 (clamped to d0), yc at d0
    const long long gm = g - ((d0 > 0) ? DS4 : 0);
    float4 ym = ld4(y, gm), pm = ld4(p, gm);
    float4 yc = ld4(y, g),  pc = ld4(p, g);

    float l1 = 0.f, gd = 0.f;

    #pragma unroll 4
    for (int i = 0; i < DC; ++i) {
        const int d = d0 + i;
        const long long gn = g + ((d < DDIM - 1) ? DS4 : 0);
        const float4 yn = ld4(y, gn);
        const float4 pn = ld4(p, gn);
        const float sd = (d == 0 || d == DDIM - 1) ? 1.f : 0.5f;

        // H neighbors at depth d (clamped offsets)
        const float4 yhm = ld4(y, g - hmo), yhp = ld4(y, g + hpo);
        const float4 phm = ld4(p, g - hmo), php = ld4(p, g + hpo);

        // W edge scalars (clamped; L1 hits — same lines as the wave's centers)
        const float* yr = y + 4LL * g;
        const float* pr = p + 4LL * g;
        const float ywl = yr[wlo], ywr = yr[wro];
        const float pwl = pr[wlo], pwr = pr[wro];

        // ---- L1 ----
        l1 += fabsf(yc.x - pc.x) + fabsf(yc.y - pc.y)
            + fabsf(yc.z - pc.z) + fabsf(yc.w - pc.w);

        float t0, gy, gp;
        // ---- W axis ----
        gy = (yc.y - ywl) * swx;  gp = (pc.y - pwl) * swx;
        t0 = fabsf(gy) - fabsf(gp); gd += t0 * t0;
        gy = (yc.z - yc.x) * 0.5f; gp = (pc.z - pc.x) * 0.5f;
        t0 = fabsf(gy) - fabsf(gp); gd += t0 * t0;
        gy = (yc.w - yc.y) * 0.5f; gp = (pc.w - pc.y) * 0.5f;
        t0 = fabsf(gy) - fabsf(gp); gd += t0 * t0;
        gy = (ywr - yc.z) * sww;  gp = (pwr - pc.z) * sww;
        t0 = fabsf(gy) - fabsf(gp); gd += t0 * t0;

        // ---- H axis ----
        t0 = fabsf((yhp.x - yhm.x) * sh) - fabsf((php.x - phm.x) * sh); gd += t0 * t0;
        t0 = fabsf((yhp.y - yhm.y) * sh) - fabsf((php.y - phm.y) * sh); gd += t0 * t0;
        t0 = fabsf((yhp.z - yhm.z) * sh) - fabsf((php.z - phm.z) * sh); gd += t0 * t0;
        t0 = fabsf((yhp.w - yhm.w) * sh) - fabsf((php.w - phm.w) * sh); gd += t0 * t0;

        // ---- D axis (registers only) ----
        t0 = fabsf((yn.x - ym.x) * sd) - fabsf((pn.x - pm.x) * sd); gd += t0 * t0;
        t0 = fabsf((yn.y - ym.y) * sd) - fabsf((pn.y - pm.y) * sd); gd += t0 * t0;
        t0 = fabsf((yn.z - ym.z) * sd) - fabsf((pn.z - pm.z) * sd); gd += t0 * t0;
        t0 = fabsf((yn.w - ym.w) * sd) - fabsf((pn.w - pm.w) * sd); gd += t0 * t0;

        // shift pipeline
        ym = yc; yc = yn; pm = pc; pc = pn; g = gn;
    }

    // ---- block reduction: wave shuffle (64 lanes) then LDS across 4 waves ----
    __shared__ float lds1[4], lds2[4];
    #pragma unroll
    for (int off = 32; off > 0; off >>= 1) {
        l1 += __shfl_down(l1, off, 64);
        gd += __shfl_down(gd, off, 64);
    }
    const int lane = threadIdx.x & 63;
    const int wave = threadIdx.x >> 6;
    if (lane == 0) { lds1[wave] = l1; lds2[wave] = gd; }
    __syncthreads();
    if (threadIdx.x == 0) {
        atomicAdd(&acc[0], lds1[0] + lds1[1] + lds1[2] + lds1[3]);
        atomicAdd(&acc[1], lds2[0] + lds2[1] + lds2[2] + lds2[3]);
    }
}

// BCE over the small discriminator tensor + final combine. Single block.
__global__ __launch_bounds__(BLOCK) void finalize_kernel(const float* __restrict__ dsc,
                                                         const float* __restrict__ acc,
                                                         float* __restrict__ out) {
    float s = 0.f;
    for (int i = threadIdx.x; i < NDSC; i += BLOCK) {
        const float x = dsc[i];
        // target is zeros: max(x,0) - x*0 + log1p(exp(-|x|))
        s += fmaxf(x, 0.f) + log1pf(expf(-fabsf(x)));
    }
    __shared__ float lds[4];
    #pragma unroll
    for (int off = 32; off > 0; off >>= 1)
        s += __shfl_down(s, off, 64);
    if ((threadIdx.x & 63) == 0) lds[threadIdx.x >> 6] = s;
    __syncthreads();
    if (threadIdx.x == 0) {
        const float bce = (lds[0] + lds[1] + lds[2] + lds[3]) / (float)NDSC;
        const float l1m = acc[0] / (float)NTOT;
        const float gdm = acc[1] / (float)NTOT;
        out[0] = bce + 100.f * (l1m + gdm);
    }
}

extern "C" void kernel_launch(void* const* d_in, const int* in_sizes, int n_in,
                              void* d_out, int out_size, void* d_ws, size_t ws_size,
                              hipStream_t stream) {
    const float* dsc_fake = (const float*)d_in[0];
    const float* predicts = (const float*)d_in[1];
    const float* y_data   = (const float*)d_in[2];
    // d_in[3] (zeros) unused: target==0 makes the -x*target term vanish.
    float* acc = (float*)d_ws;
    float* out = (float*)d_out;

    hipMemsetAsync(d_ws, 0, 2 * sizeof(float), stream);
    vol_kernel<<<GRID, BLOCK, 0, stream>>>(predicts, y_data, acc);
    finalize_kernel<<<1, BLOCK, 0, stream>>>(dsc_fake, acc, out);
}

// Round 3
// 192.377 us; speedup vs baseline: 1.4187x; 1.1294x over previous
//
#include <hip/hip_runtime.h>
#include <math.h>

namespace {
constexpr int BATCH = 4;
constexpr int DDIM  = 128;
constexpr int HDIM  = 192;
constexpr int WDIM  = 192;
constexpr long long NTOT = (long long)BATCH * DDIM * HDIM * WDIM; // 18,874,368
constexpr int GW   = WDIM / 4;            // 48 float4 groups per W-row
constexpr int HS4  = GW;                  // group stride for h +/- 1
constexpr int DS4  = GW * HDIM;           // group stride for d +/- 1 (9216)
constexpr int NDSC = 4 * 1 * 8 * 12 * 12; // 4608
constexpr int BLOCK = 256;
constexpr int DC    = 8;                  // depth steps per thread
constexpr int NCH   = DDIM / DC;          // 16 chunks
constexpr int NCOL  = BATCH * HDIM * GW;  // 36,864 columns
constexpr int NTHREADS = NCOL * NCH;      // 589,824
constexpr int GRID  = NTHREADS / BLOCK;   // 2304 blocks = exactly 9 per CU
}

__device__ __forceinline__ float4 ld4(const float* __restrict__ p, long long g) {
    return *(const float4*)(p + 4LL * g);
}

// One thread per (b,h,gw) float4 column x 8 depth steps. Register pipeline
// along D (no D-neighbor loads) + explicit one-step-ahead prefetch of all
// loads so ~10 vmem ops are in flight during every compute phase.
// Branchless np.gradient edges: neighbor offset clamped to center, scale 1
// at edges / 0.5 interior.
__global__ __launch_bounds__(BLOCK) void vol_kernel(const float* __restrict__ p,
                                                    const float* __restrict__ y,
                                                    float* __restrict__ part) {
    const int t   = blockIdx.x * BLOCK + threadIdx.x;
    const int gw  = t % GW;
    int rest      = t / GW;
    const int h   = rest % HDIM; rest /= HDIM;
    const int b   = rest % BATCH;
    const int d0  = (rest / BATCH) * DC;

    const int   hmo = (h > 0)        ? HS4 : 0;
    const int   hpo = (h < HDIM - 1) ? HS4 : 0;
    const float sh  = (h == 0 || h == HDIM - 1) ? 1.f : 0.5f;
    const int   wlo = (gw > 0)       ? -1 : 0;
    const int   wro = (gw < GW - 1)  ? 4 : 3;
    const float swx = (gw == 0)      ? 1.f : 0.5f;
    const float sww = (gw == GW - 1) ? 1.f : 0.5f;

    long long g = (((long long)b * DDIM + d0) * HDIM + h) * GW + gw;

    // ---- pipeline init at depth d0 ----
    const long long gm = g - ((d0 > 0) ? DS4 : 0);
    float4 ym = ld4(y, gm), pm = ld4(p, gm);
    float4 yc = ld4(y, g),  pc = ld4(p, g);
    long long gn = g + DS4;                    // d0+1 <= 121 < 128 always
    float4 yn = ld4(y, gn), pn = ld4(p, gn);
    float4 yhm = ld4(y, g - hmo), yhp = ld4(y, g + hpo);
    float4 phm = ld4(p, g - hmo), php = ld4(p, g + hpo);
    float ywl = y[4LL * g + wlo], ywr = y[4LL * g + wro];
    float pwl = p[4LL * g + wlo], pwr = p[4LL * g + wro];

    float l1 = 0.f, gd = 0.f;

    #pragma unroll
    for (int i = 0; i < DC; ++i) {
        const int d = d0 + i;

        // ---- prefetch everything for step i+1 (compile-time guard) ----
        float4 ynn, pnn, yhm2, yhp2, phm2, php2;
        float ywl2, ywr2, pwl2, pwr2;
        long long gnn = gn;
        if (i < DC - 1) {
            gnn = gn + ((d + 2 < DDIM) ? DS4 : 0);
            ynn  = ld4(y, gnn);      pnn  = ld4(p, gnn);
            yhm2 = ld4(y, gn - hmo); yhp2 = ld4(y, gn + hpo);
            phm2 = ld4(p, gn - hmo); php2 = ld4(p, gn + hpo);
            ywl2 = y[4LL * gn + wlo]; ywr2 = y[4LL * gn + wro];
            pwl2 = p[4LL * gn + wlo]; pwr2 = p[4LL * gn + wro];
        }

        const float sd = (d == 0 || d == DDIM - 1) ? 1.f : 0.5f;

        // ---- L1 ----
        l1 += fabsf(yc.x - pc.x) + fabsf(yc.y - pc.y)
            + fabsf(yc.z - pc.z) + fabsf(yc.w - pc.w);

        float t0, gy, gp;
        // ---- W axis ----
        gy = (yc.y - ywl) * swx;  gp = (pc.y - pwl) * swx;
        t0 = fabsf(gy) - fabsf(gp); gd += t0 * t0;
        gy = (yc.z - yc.x) * 0.5f; gp = (pc.z - pc.x) * 0.5f;
        t0 = fabsf(gy) - fabsf(gp); gd += t0 * t0;
        gy = (yc.w - yc.y) * 0.5f; gp = (pc.w - pc.y) * 0.5f;
        t0 = fabsf(gy) - fabsf(gp); gd += t0 * t0;
        gy = (ywr - yc.z) * sww;  gp = (pwr - pc.z) * sww;
        t0 = fabsf(gy) - fabsf(gp); gd += t0 * t0;

        // ---- H axis ----
        t0 = fabsf((yhp.x - yhm.x) * sh) - fabsf((php.x - phm.x) * sh); gd += t0 * t0;
        t0 = fabsf((yhp.y - yhm.y) * sh) - fabsf((php.y - phm.y) * sh); gd += t0 * t0;
        t0 = fabsf((yhp.z - yhm.z) * sh) - fabsf((php.z - phm.z) * sh); gd += t0 * t0;
        t0 = fabsf((yhp.w - yhm.w) * sh) - fabsf((php.w - phm.w) * sh); gd += t0 * t0;

        // ---- D axis (registers only) ----
        t0 = fabsf((yn.x - ym.x) * sd) - fabsf((pn.x - pm.x) * sd); gd += t0 * t0;
        t0 = fabsf((yn.y - ym.y) * sd) - fabsf((pn.y - pm.y) * sd); gd += t0 * t0;
        t0 = fabsf((yn.z - ym.z) * sd) - fabsf((pn.z - pm.z) * sd); gd += t0 * t0;
        t0 = fabsf((yn.w - ym.w) * sd) - fabsf((pn.w - pm.w) * sd); gd += t0 * t0;

        // ---- shift pipeline ----
        if (i < DC - 1) {
            ym = yc; yc = yn; yn = ynn;
            pm = pc; pc = pn; pn = pnn;
            yhm = yhm2; yhp = yhp2; phm = phm2; php = php2;
            ywl = ywl2; ywr = ywr2; pwl = pwl2; pwr = pwr2;
            g = gn; gn = gnn;
        }
    }

    // ---- block reduction, then one partial pair per block (no atomics) ----
    __shared__ float lds1[4], lds2[4];
    #pragma unroll
    for (int off = 32; off > 0; off >>= 1) {
        l1 += __shfl_down(l1, off, 64);
        gd += __shfl_down(gd, off, 64);
    }
    if ((threadIdx.x & 63) == 0) {
        lds1[threadIdx.x >> 6] = l1;
        lds2[threadIdx.x >> 6] = gd;
    }
    __syncthreads();
    if (threadIdx.x == 0) {
        part[2 * blockIdx.x]     = lds1[0] + lds1[1] + lds1[2] + lds1[3];
        part[2 * blockIdx.x + 1] = lds2[0] + lds2[1] + lds2[2] + lds2[3];
    }
}

// Reduce per-block partials + BCE over the small discriminator tensor.
__global__ __launch_bounds__(BLOCK) void finalize_kernel(const float* __restrict__ dsc,
                                                         const float* __restrict__ part,
                                                         float* __restrict__ out) {
    float l1 = 0.f, gd = 0.f, s = 0.f;
    for (int i = threadIdx.x; i < GRID; i += BLOCK) {
        l1 += part[2 * i];
        gd += part[2 * i + 1];
    }
    for (int i = threadIdx.x; i < NDSC; i += BLOCK) {
        const float x = dsc[i];
        // target is zeros: max(x,0) - x*0 + log1p(exp(-|x|))
        s += fmaxf(x, 0.f) + log1pf(expf(-fabsf(x)));
    }
    __shared__ float a[4], c[4], e[4];
    #pragma unroll
    for (int off = 32; off > 0; off >>= 1) {
        l1 += __shfl_down(l1, off, 64);
        gd += __shfl_down(gd, off, 64);
        s  += __shfl_down(s,  off, 64);
    }
    if ((threadIdx.x & 63) == 0) {
        const int w = threadIdx.x >> 6;
        a[w] = l1; c[w] = gd; e[w] = s;
    }
    __syncthreads();
    if (threadIdx.x == 0) {
        const float bce = (e[0] + e[1] + e[2] + e[3]) / (float)NDSC;
        const float l1m = (a[0] + a[1] + a[2] + a[3]) / (float)NTOT;
        const float gdm = (c[0] + c[1] + c[2] + c[3]) / (float)NTOT;
        out[0] = bce + 100.f * (l1m + gdm);
    }
}

extern "C" void kernel_launch(void* const* d_in, const int* in_sizes, int n_in,
                              void* d_out, int out_size, void* d_ws, size_t ws_size,
                              hipStream_t stream) {
    const float* dsc_fake = (const float*)d_in[0];
    const float* predicts = (const float*)d_in[1];
    const float* y_data   = (const float*)d_in[2];
    // d_in[3] (zeros) unused: target==0 makes the -x*target term vanish.
    float* part = (float*)d_ws;   // GRID*2 floats, fully overwritten each call
    float* out  = (float*)d_out;

    vol_kernel<<<GRID, BLOCK, 0, stream>>>(predicts, y_data, part);
    finalize_kernel<<<1, BLOCK, 0, stream>>>(dsc_fake, part, out);
}